// Round 1
// 9348.752 us; speedup vs baseline: 1.4091x; 1.4091x over previous
//
#include <hip/hip_runtime.h>
#include <cmath>

#define BB 128
#define TT 365
#define DD 32
#define HH 512
#define G4H 2048  // 4*HH

// ws layout (floats): buf0 [0,65536) | buf1 [65536,131072) | bar [131072,+256 uints)
//                     | cst [131328, +65536) (fallback only)
// hipMemsetAsync zeroes [0, 787456) bytes each call.

__device__ __forceinline__ float sigf(float z) { return 1.f / (1.f + __expf(-z)); }

// ---------------------------------------------------------------------------
// Persistent kernel v2: 256 WGs x 512 threads = 8 batch-groups (16 rows each)
// x 32 col-WGs (16 h-cols -> 64 gate-cols each). Column replication per group
// drops 128 -> 32 => 4x less agent-coherent h traffic (32MB -> 8MB per step),
// 4x fewer barrier arrivals (32 per group). W slice (64 x 548, K=D+H=544)
// stays in LDS all 365 steps; 162.6KB LDS -> 1 WG/CU (8 waves, same as v1's
// 2x4). Thread tile 4 rows x 4 gate-cols, K-split 8 (ks=tid&7, intra-wave
// shuffle reduce). Ash stride 132 / Xs stride 36 kill the 8-way A-read bank
// conflict v1 had (2.05e8 conflict cycles).
// ---------------------------------------------------------------------------
__global__ __launch_bounds__(512, 2)
void lstm_persistent(const float* __restrict__ x,
                     const float* __restrict__ Wx,
                     const float* __restrict__ Wh,
                     const float* __restrict__ bias,
                     float* __restrict__ out,
                     float* __restrict__ hws) {
  __shared__ __align__(16) float Wl[64 * 548];      // 140288 B, row stride 548 (16B-aligned, conflict-free reads)
  __shared__ __align__(16) float Ash[2][16 * 132];  // 16896 B, double-buffered h chunk (128 k-floats + pad)
  __shared__ __align__(16) float ZxS[4 * 16 * 16];  // 4096 B; first 576 floats alias Xs[16][36]
  __shared__ __align__(16) float Cs[16][16];        // 1024 B cell state
  __shared__ __align__(16) float BiasS[64];
  // total 162560 B -> 1 WG/CU

  const int tid = threadIdx.x;
  const int ks = tid & 7;          // K-split: contiguous float4 per lane
  const int btile = (tid >> 3) & 3;  // 4 row-tiles x 4 rows = 16 rows
  const int ctile = tid >> 5;        // 16 col-tiles x 4 gate-cols = 64 cols
  const int wg = blockIdx.x;
  const int bb = wg & 7;           // batch group (32 WGs land on one XCD)
  const int nb = wg >> 3;          // col-WG [0,32)
  const int b0g = bb * 16;
  const int n0 = nb * 16;

  // ---- stage weights: lanes 0..15 read 16 consecutive cols (64B coalesced)
  {
    const int cl = tid & 15;
    const int pg = tid >> 4;  // [0,32) covers (k,g) pairs
    for (int it = 0; it < 68; ++it) {
      int p = it * 32 + pg;  // [0, 544*4)
      int k = p >> 2, g = p & 3;
      int col = g * HH + n0 + cl;
      float v = (k < DD) ? Wx[k * G4H + col] : Wh[(k - DD) * G4H + col];
      Wl[(g * 16 + cl) * 548 + k] = v;
    }
  }
  if (tid < 64) BiasS[tid] = bias[(tid >> 4) * HH + n0 + (tid & 15)];
  if (tid < 256) Cs[tid >> 4][tid & 15] = 0.f;

  float* buf0 = hws;
  float* buf1 = hws + BB * HH;
  unsigned int* bar = (unsigned int*)(hws + 2 * BB * HH) + bb * 32;

  const int bl5 = tid >> 5;  // h-load row [0,16)
  const int kq5 = tid & 31;  // ull offset within 64-float half-chunk

  __syncthreads();  // Wl ready (h0 = 0 comes from host-side memset)

  for (int t = 0; t < TT; ++t) {
    const float* hprev = (t & 1) ? buf1 : buf0;
    float* hnext = (t & 1) ? buf0 : buf1;

    // ---- issue ALL h loads up front (agent-scope 64-bit atomics, L3-coherent);
    //      chunks 1..3 latency hides under chunk 0..2 compute
    unsigned long long pre[8];
#pragma unroll
    for (int r = 0; r < 8; ++r) {
      pre[r] = __hip_atomic_load(
          (const unsigned long long*)(hprev + (size_t)(b0g + bl5) * HH +
                                      r * 64 + kq5 * 2),
          __ATOMIC_RELAXED, __HIP_MEMORY_SCOPE_AGENT);
    }
    // ---- stage x slice (Xs aliases ZxS, row stride 36)
    if (tid < 128) {
      int b_l = tid >> 3, kq = tid & 7;
      float4 v =
          *(const float4*)(x + ((size_t)(b0g + b_l) * TT + t) * DD + kq * 4);
      *(float4*)&ZxS[b_l * 36 + kq * 4] = v;
    }
    // ---- chunk 0 -> Ash[0]
    *(unsigned long long*)&Ash[0][bl5 * 132 + kq5 * 2] = pre[0];
    *(unsigned long long*)&Ash[0][bl5 * 132 + 64 + kq5 * 2] = pre[1];
    __syncthreads();

    float acc[4][4];
#pragma unroll
    for (int i = 0; i < 4; ++i)
#pragma unroll
      for (int c = 0; c < 4; ++c) acc[i][c] = 0.f;

    auto mac4 = [&](const float* Abase, int rstride, const float* Wbase) {
      float4 a4[4], w4[4];
#pragma unroll
      for (int i = 0; i < 4; ++i)
        a4[i] = *(const float4*)(Abase + (btile * 4 + i) * rstride);
#pragma unroll
      for (int c = 0; c < 4; ++c) w4[c] = *(const float4*)(Wbase + c * 548);
#pragma unroll
      for (int i = 0; i < 4; ++i)
#pragma unroll
        for (int c = 0; c < 4; ++c)
          acc[i][c] += a4[i].x * w4[c].x + a4[i].y * w4[c].y +
                       a4[i].z * w4[c].z + a4[i].w * w4[c].w;
    };

#pragma unroll
    for (int ch = 0; ch < 4; ++ch) {
      if (ch == 0) mac4(&ZxS[ks * 4], 36, &Wl[(ctile * 4) * 548 + ks * 4]);
#pragma unroll
      for (int j = 0; j < 4; ++j)
        mac4(&Ash[ch & 1][j * 32 + ks * 4], 132,
             &Wl[(ctile * 4) * 548 + DD + ch * 128 + j * 32 + ks * 4]);
      if (ch < 3) {
        *(unsigned long long*)&Ash[(ch + 1) & 1][bl5 * 132 + kq5 * 2] =
            pre[2 * ch + 2];
        *(unsigned long long*)&Ash[(ch + 1) & 1][bl5 * 132 + 64 + kq5 * 2] =
            pre[2 * ch + 3];
      }
      __syncthreads();
    }

    // reduce over ks (lane bits 0..2, intra-wave)
#pragma unroll
    for (int i = 0; i < 4; ++i)
#pragma unroll
      for (int c = 0; c < 4; ++c) {
        float v = acc[i][c];
        v += __shfl_xor(v, 1);
        v += __shfl_xor(v, 2);
        v += __shfl_xor(v, 4);
        acc[i][c] = v;
      }

    if (ks == 0) {
#pragma unroll
      for (int i = 0; i < 4; ++i)
#pragma unroll
        for (int c = 0; c < 4; ++c) {
          int zc = ctile * 4 + c;
          ZxS[((zc >> 4) * 16 + btile * 4 + i) * 16 + (zc & 15)] =
              acc[i][c] + BiasS[zc];
        }
    }
    __syncthreads();

    if (tid < 256) {
      int b_l = tid >> 4, nn = tid & 15;
      float zi = ZxS[(0 * 16 + b_l) * 16 + nn];
      float zf = ZxS[(1 * 16 + b_l) * 16 + nn];
      float zg = ZxS[(2 * 16 + b_l) * 16 + nn];
      float zo = ZxS[(3 * 16 + b_l) * 16 + nn];
      float cnew = sigf(zf) * Cs[b_l][nn] + sigf(zi) * tanhf(zg);
      Cs[b_l][nn] = cnew;
      float hv = sigf(zo) * tanhf(cnew);
      int bg = b0g + b_l, col = n0 + nn;
      __hip_atomic_store(&hnext[(size_t)bg * HH + col], hv, __ATOMIC_RELAXED,
                         __HIP_MEMORY_SCOPE_AGENT);
      out[((size_t)bg * TT + t) * HH + col] = hv;  // 64B per row, coalesced
    }
    __syncthreads();  // drains vmcnt(0): h stores at L3 before anyone arrives

    // per-group barrier: monotonic counter, 32 WGs
    if (tid == 0) {
      __hip_atomic_fetch_add(bar, 1u, __ATOMIC_RELAXED,
                             __HIP_MEMORY_SCOPE_AGENT);
      unsigned int target = 32u * (unsigned)(t + 1);
      while (__hip_atomic_load(bar, __ATOMIC_RELAXED,
                               __HIP_MEMORY_SCOPE_AGENT) < target) {
      }
    }
    __syncthreads();
  }
}

// ---------------------------------------------------------------------------
// Fallback: one launch per timestep (kernel-boundary coherence). Only used if
// the cooperative launch is rejected. (v1 geometry: 512 WGs x 256 threads.)
// ---------------------------------------------------------------------------
__global__ __launch_bounds__(256, 2)
void lstm_step(const float* __restrict__ x, const float* __restrict__ Wx,
               const float* __restrict__ Wh, const float* __restrict__ bias,
               float* __restrict__ out, const float* __restrict__ hprev,
               float* __restrict__ hnext, float* __restrict__ cst, int t) {
  __shared__ float Wl[16 * 544];
  __shared__ float Ash[32 * 128];
  __shared__ float Xs[32 * 32];
  __shared__ float Zx[4][32][4];
  __shared__ float BiasS[16];

  const int tid = threadIdx.x;
  const int ks = tid & 7;
  const int btile = (tid >> 3) & 7;
  const int ctile = tid >> 6;
  const int wg = blockIdx.x;
  const int bb = wg & 3;
  const int nb = wg >> 2;
  const int b0g = bb * 32;
  const int n0 = nb * 4;

  for (int idx = tid; idx < 16 * 544; idx += 256) {
    int zc = idx & 15, k = idx >> 4;
    int col = (zc >> 2) * HH + n0 + (zc & 3);
    Wl[zc * 544 + k] = (k < DD) ? Wx[k * G4H + col] : Wh[(k - DD) * G4H + col];
  }
  if (tid < 16) BiasS[tid] = bias[(tid >> 2) * HH + n0 + (tid & 3)];

  {
    int b_l = tid >> 3, kq = tid & 7;
    float4 v = *(const float4*)(x + ((size_t)(b0g + b_l) * TT + t) * DD + kq * 4);
    *(float4*)&Xs[b_l * 32 + kq * 4] = v;
  }

  float acc[4][4];
#pragma unroll
  for (int i = 0; i < 4; ++i)
#pragma unroll
    for (int c = 0; c < 4; ++c) acc[i][c] = 0.f;

  auto mac4 = [&](const float* Abase, int rstride, const float* Wbase) {
    float4 a4[4], w4[4];
#pragma unroll
    for (int i = 0; i < 4; ++i)
      a4[i] = *(const float4*)(Abase + (btile * 4 + i) * rstride);
#pragma unroll
    for (int c = 0; c < 4; ++c) w4[c] = *(const float4*)(Wbase + c * 544);
#pragma unroll
    for (int i = 0; i < 4; ++i)
#pragma unroll
      for (int c = 0; c < 4; ++c)
        acc[i][c] += a4[i].x * w4[c].x + a4[i].y * w4[c].y +
                     a4[i].z * w4[c].z + a4[i].w * w4[c].w;
  };

  for (int ch = 0; ch < 4; ++ch) {
    __syncthreads();
    for (int r = 0; r < 4; ++r) {
      int fidx = r * 256 + tid;
      int b_l = fidx >> 5, kq = fidx & 31;
      float4 v = *(const float4*)(hprev + (size_t)(b0g + b_l) * HH + ch * 128 +
                                  kq * 4);
      *(float4*)&Ash[b_l * 128 + kq * 4] = v;
    }
    __syncthreads();
    if (ch == 0) mac4(&Xs[ks * 4], 32, &Wl[(ctile * 4) * 544 + ks * 4]);
#pragma unroll
    for (int j = 0; j < 4; ++j)
      mac4(&Ash[j * 32 + ks * 4], 128,
           &Wl[(ctile * 4) * 544 + DD + ch * 128 + j * 32 + ks * 4]);
  }

#pragma unroll
  for (int i = 0; i < 4; ++i)
#pragma unroll
    for (int c = 0; c < 4; ++c) {
      float v = acc[i][c];
      v += __shfl_xor(v, 1);
      v += __shfl_xor(v, 2);
      v += __shfl_xor(v, 4);
      acc[i][c] = v;
    }

  if (ks == 0) {
#pragma unroll
    for (int i = 0; i < 4; ++i)
#pragma unroll
      for (int c = 0; c < 4; ++c)
        Zx[ctile][btile * 4 + i][c] = acc[i][c] + BiasS[ctile * 4 + c];
  }
  __syncthreads();

  if (tid < 128) {
    int b_l = tid >> 2, nn = tid & 3;
    float zi = Zx[0][b_l][nn], zf = Zx[1][b_l][nn];
    float zg = Zx[2][b_l][nn], zo = Zx[3][b_l][nn];
    int bg = b0g + b_l, col = n0 + nn;
    size_t cidx = (size_t)bg * HH + col;
    float cnew = sigf(zf) * cst[cidx] + sigf(zi) * tanhf(zg);
    cst[cidx] = cnew;
    float hv = sigf(zo) * tanhf(cnew);
    hnext[cidx] = hv;
    out[((size_t)bg * TT + t) * HH + col] = hv;
  }
}

extern "C" void kernel_launch(void* const* d_in, const int* in_sizes, int n_in,
                              void* d_out, int out_size, void* d_ws, size_t ws_size,
                              hipStream_t stream) {
  const float* x = (const float*)d_in[0];
  const float* Wx = (const float*)d_in[1];
  const float* Wh = (const float*)d_in[2];
  const float* bv = (const float*)d_in[3];
  float* out = (float*)d_out;
  float* hws = (float*)d_ws;

  // zero: buf0 | buf1 | barrier counters | cst  = (3*65536 + 256) * 4 bytes
  hipMemsetAsync(d_ws, 0, (size_t)(3 * 65536 + 256) * 4, stream);

  void* args[] = {(void*)&x, (void*)&Wx, (void*)&Wh,
                  (void*)&bv, (void*)&out, (void*)&hws};
  hipError_t err = hipLaunchCooperativeKernel(
      reinterpret_cast<void*>(lstm_persistent), dim3(256), dim3(512), args, 0,
      stream);
  if (err != hipSuccess) {
    (void)hipGetLastError();
    float* buf0 = hws;
    float* buf1 = hws + BB * HH;
    float* cst = hws + 2 * BB * HH + 256;
    for (int t = 0; t < TT; ++t) {
      const float* hp = (t & 1) ? buf1 : buf0;
      float* hn = (t & 1) ? buf0 : buf1;
      lstm_step<<<dim3(512), dim3(256), 0, stream>>>(x, Wx, Wh, bv, out, hp, hn,
                                                     cst, t);
    }
  }
}

// Round 5
// 7494.962 us; speedup vs baseline: 1.7576x; 1.2473x over previous
//
#include <hip/hip_runtime.h>
#include <hip/hip_fp16.h>
#include <cmath>

#define BB 128
#define TT 365
#define DD 32
#define HH 512
#define G4H 2048  // 4*HH

// ws layout: buf0 fp16 at byte 0 (131072B used of 262144B slot)
//            buf1 fp16 at byte 262144 (float-ofs 65536)
//            bar  at byte 524288 (float-ofs 131072, 256 uints)
//            cst  at float-ofs 131328 (fallback only, fp32)
// hipMemsetAsync zeroes [0, 787456) bytes each call (fp16 zero == 0 bits).

typedef float f32x4 __attribute__((ext_vector_type(4)));

__device__ __forceinline__ float sigf(float z) { return 1.f / (1.f + __expf(-z)); }

// ---------------------------------------------------------------------------
// Persistent kernel v6: structure and EVERY coherence-relevant instruction
// identical to v2 (9349us, passed): agent-scope __hip_atomic_load/store for
// the h exchange, v2's monotonic-counter barrier, vmcnt-drain ordering via
// __syncthreads. Change is PAYLOAD ONLY: h is exchanged as fp16. v2's
// counters showed the step time == atomic-op count x ~75B fabric cost
// (1.05M 8B-loads + 64K 4B-stores = 84MB/step at 3.2TB/s = 26us). fp16
// packing halves load ops (4 ull/thread instead of 8) and quarters store
// ops (4 cols per 8B store via intra-wave shfl). Accuracy: fp16 h err
// ~2.4e-4/step, contracted by the forget gate -> ~1e-3 final, threshold
// 1.92e-2. c stays fp32 in LDS; out written fp32 from unquantized hv.
// ---------------------------------------------------------------------------
__global__ __launch_bounds__(512, 2)
void lstm_persistent(const float* __restrict__ x,
                     const float* __restrict__ Wx,
                     const float* __restrict__ Wh,
                     const float* __restrict__ bias,
                     float* __restrict__ out,
                     float* __restrict__ hws) {
  __shared__ __align__(16) float Wl[64 * 548];      // 140288 B
  __shared__ __align__(16) float Ash[2][16 * 132];  // 16896 B, double-buffered h chunk
  __shared__ __align__(16) float ZxS[4 * 16 * 16];  // 4096 B; first 576 floats alias Xs[16][36]
  __shared__ __align__(16) float Cs[16][16];        // 1024 B
  __shared__ __align__(16) float BiasS[64];
  // total ~162.6 KB -> 1 WG/CU

  const int tid = threadIdx.x;
  const int ks = tid & 7;
  const int btile = (tid >> 3) & 3;
  const int ctile = tid >> 5;
  const int wg = blockIdx.x;
  const int bb = wg & 7;   // batch group
  const int nb = wg >> 3;  // col-WG [0,32)
  const int b0g = bb * 16;
  const int n0 = nb * 16;

  // ---- stage weights: lanes 0..15 read 16 consecutive cols (64B coalesced)
  {
    const int cl = tid & 15;
    const int pg = tid >> 4;
    for (int it = 0; it < 68; ++it) {
      int p = it * 32 + pg;
      int k = p >> 2, g = p & 3;
      int col = g * HH + n0 + cl;
      float v = (k < DD) ? Wx[k * G4H + col] : Wh[(k - DD) * G4H + col];
      Wl[(g * 16 + cl) * 548 + k] = v;
    }
  }
  if (tid < 64) BiasS[tid] = bias[(tid >> 4) * HH + n0 + (tid & 15)];
  if (tid < 256) Cs[tid >> 4][tid & 15] = 0.f;

  __half* hb0 = (__half*)hws;                  // fp16 h buffers
  __half* hb1 = (__half*)(hws + BB * HH);
  unsigned int* bar = (unsigned int*)(hws + 2 * BB * HH) + bb * 32;

  const int bl5 = tid >> 5;  // h row [0,16)
  const int kq5 = tid & 31;  // ull index within a 128-value chunk (4 fp16/ull)

  auto unpk = [](unsigned long long u) {
    union { unsigned long long ull; __half h[4]; } c;
    c.ull = u;
    f32x4 v;
    v.x = __half2float(c.h[0]);
    v.y = __half2float(c.h[1]);
    v.z = __half2float(c.h[2]);
    v.w = __half2float(c.h[3]);
    return v;
  };

  __syncthreads();  // Wl ready (h0 = 0 from host-side memset)

  for (int t = 0; t < TT; ++t) {
    const __half* hprev = (t & 1) ? hb1 : hb0;
    __half* hnext = (t & 1) ? hb0 : hb1;

    // ---- stage x slice (plain cached loads; Xs aliases ZxS, row stride 36)
    if (tid < 128) {
      int b_l = tid >> 3, kq = tid & 7;
      f32x4 v =
          *(const f32x4*)(x + ((size_t)(b0g + b_l) * TT + t) * DD + kq * 4);
      *(f32x4*)&ZxS[b_l * 36 + kq * 4] = v;
    }
    // ---- h loads: 4 agent-scope 8B atomic loads/thread (4 fp16 each);
    //      identical op class to v2, half the op count
    unsigned long long pre[4];
    {
      const __half* hp16 = hprev + (size_t)(b0g + bl5) * HH + kq5 * 4;
#pragma unroll
      for (int r = 0; r < 4; ++r)
        pre[r] = __hip_atomic_load((const unsigned long long*)(hp16 + r * 128),
                                   __ATOMIC_RELAXED, __HIP_MEMORY_SCOPE_AGENT);
    }
    *(f32x4*)&Ash[0][bl5 * 132 + kq5 * 4] = unpk(pre[0]);
    __syncthreads();

    float acc[4][4];
#pragma unroll
    for (int i = 0; i < 4; ++i)
#pragma unroll
      for (int c = 0; c < 4; ++c) acc[i][c] = 0.f;

    auto mac4 = [&](const float* Abase, int rstride, const float* Wbase) {
      f32x4 a4[4], w4[4];
#pragma unroll
      for (int i = 0; i < 4; ++i)
        a4[i] = *(const f32x4*)(Abase + (btile * 4 + i) * rstride);
#pragma unroll
      for (int c = 0; c < 4; ++c) w4[c] = *(const f32x4*)(Wbase + c * 548);
#pragma unroll
      for (int i = 0; i < 4; ++i)
#pragma unroll
        for (int c = 0; c < 4; ++c)
          acc[i][c] += a4[i].x * w4[c].x + a4[i].y * w4[c].y +
                       a4[i].z * w4[c].z + a4[i].w * w4[c].w;
    };

#pragma unroll
    for (int ch = 0; ch < 4; ++ch) {
      if (ch == 0) mac4(&ZxS[ks * 4], 36, &Wl[(ctile * 4) * 548 + ks * 4]);
#pragma unroll
      for (int j = 0; j < 4; ++j)
        mac4(&Ash[ch & 1][j * 32 + ks * 4], 132,
             &Wl[(ctile * 4) * 548 + DD + ch * 128 + j * 32 + ks * 4]);
      if (ch < 3)
        *(f32x4*)&Ash[(ch + 1) & 1][bl5 * 132 + kq5 * 4] = unpk(pre[ch + 1]);
      __syncthreads();
    }

    // reduce over ks (lane bits 0..2, intra-wave)
#pragma unroll
    for (int i = 0; i < 4; ++i)
#pragma unroll
      for (int c = 0; c < 4; ++c) {
        float v = acc[i][c];
        v += __shfl_xor(v, 1);
        v += __shfl_xor(v, 2);
        v += __shfl_xor(v, 4);
        acc[i][c] = v;
      }

    if (ks == 0) {
#pragma unroll
      for (int i = 0; i < 4; ++i)
#pragma unroll
        for (int c = 0; c < 4; ++c) {
          int zc = ctile * 4 + c;
          ZxS[((zc >> 4) * 16 + btile * 4 + i) * 16 + (zc & 15)] =
              acc[i][c] + BiasS[zc];
        }
    }
    __syncthreads();

    if (tid < 256) {
      int b_l = tid >> 4, nn = tid & 15;
      float zi = ZxS[(0 * 16 + b_l) * 16 + nn];
      float zf = ZxS[(1 * 16 + b_l) * 16 + nn];
      float zg = ZxS[(2 * 16 + b_l) * 16 + nn];
      float zo = ZxS[(3 * 16 + b_l) * 16 + nn];
      float cnew = sigf(zf) * Cs[b_l][nn] + sigf(zi) * tanhf(zg);
      Cs[b_l][nn] = cnew;
      float hv = sigf(zo) * tanhf(cnew);
      int bg = b0g + b_l, col = n0 + nn;
      out[((size_t)bg * TT + t) * HH + col] = hv;  // fp32, 64B/row, coalesced
      // ---- pack 4 consecutive cols into ONE 8B agent-scope atomic store.
      // tid<256 = waves 0..3, full waves; lanes (b_l&3)*16+nn within wave.
      int lane = tid & 63;
      int base = lane & ~3;
      float h0 = __shfl(hv, base + 0);
      float h1 = __shfl(hv, base + 1);
      float h2 = __shfl(hv, base + 2);
      float h3 = __shfl(hv, base + 3);
      if ((lane & 3) == 0) {
        union { unsigned long long ull; __half h[4]; } pk;
        pk.h[0] = __float2half_rn(h0);
        pk.h[1] = __float2half_rn(h1);
        pk.h[2] = __float2half_rn(h2);
        pk.h[3] = __float2half_rn(h3);
        __hip_atomic_store(
            (unsigned long long*)(hnext + (size_t)bg * HH + col), pk.ull,
            __ATOMIC_RELAXED, __HIP_MEMORY_SCOPE_AGENT);
      }
    }
    __syncthreads();  // drains vmcnt(0): h stores at coherence point

    // per-group barrier (32 WGs): v2's exact proven agent-scope barrier
    if (tid == 0) {
      __hip_atomic_fetch_add(bar, 1u, __ATOMIC_RELAXED,
                             __HIP_MEMORY_SCOPE_AGENT);
      unsigned int target = 32u * (unsigned)(t + 1);
      while (__hip_atomic_load(bar, __ATOMIC_RELAXED,
                               __HIP_MEMORY_SCOPE_AGENT) < target) {
      }
    }
    __syncthreads();
  }
}

// ---------------------------------------------------------------------------
// Fallback: one launch per timestep (kernel-boundary coherence, fp32 h).
// Only used if the cooperative launch is rejected.
// ---------------------------------------------------------------------------
__global__ __launch_bounds__(256, 2)
void lstm_step(const float* __restrict__ x, const float* __restrict__ Wx,
               const float* __restrict__ Wh, const float* __restrict__ bias,
               float* __restrict__ out, const float* __restrict__ hprev,
               float* __restrict__ hnext, float* __restrict__ cst, int t) {
  __shared__ float Wl[16 * 544];
  __shared__ float Ash[32 * 128];
  __shared__ float Xs[32 * 32];
  __shared__ float Zx[4][32][4];
  __shared__ float BiasS[16];

  const int tid = threadIdx.x;
  const int ks = tid & 7;
  const int btile = (tid >> 3) & 7;
  const int ctile = tid >> 6;
  const int wg = blockIdx.x;
  const int bb = wg & 3;
  const int nb = wg >> 2;
  const int b0g = bb * 32;
  const int n0 = nb * 4;

  for (int idx = tid; idx < 16 * 544; idx += 256) {
    int zc = idx & 15, k = idx >> 4;
    int col = (zc >> 2) * HH + n0 + (zc & 3);
    Wl[zc * 544 + k] = (k < DD) ? Wx[k * G4H + col] : Wh[(k - DD) * G4H + col];
  }
  if (tid < 16) BiasS[tid] = bias[(tid >> 2) * HH + n0 + (tid & 3)];

  {
    int b_l = tid >> 3, kq = tid & 7;
    float4 v = *(const float4*)(x + ((size_t)(b0g + b_l) * TT + t) * DD + kq * 4);
    *(float4*)&Xs[b_l * 32 + kq * 4] = v;
  }

  float acc[4][4];
#pragma unroll
  for (int i = 0; i < 4; ++i)
#pragma unroll
    for (int c = 0; c < 4; ++c) acc[i][c] = 0.f;

  auto mac4 = [&](const float* Abase, int rstride, const float* Wbase) {
    float4 a4[4], w4[4];
#pragma unroll
    for (int i = 0; i < 4; ++i)
      a4[i] = *(const float4*)(Abase + (btile * 4 + i) * rstride);
#pragma unroll
    for (int c = 0; c < 4; ++c) w4[c] = *(const float4*)(Wbase + c * 544);
#pragma unroll
    for (int i = 0; i < 4; ++i)
#pragma unroll
      for (int c = 0; c < 4; ++c)
        acc[i][c] += a4[i].x * w4[c].x + a4[i].y * w4[c].y +
                     a4[i].z * w4[c].z + a4[i].w * w4[c].w;
  };

  for (int ch = 0; ch < 4; ++ch) {
    __syncthreads();
    for (int r = 0; r < 4; ++r) {
      int fidx = r * 256 + tid;
      int b_l = fidx >> 5, kq = fidx & 31;
      float4 v = *(const float4*)(hprev + (size_t)(b0g + b_l) * HH + ch * 128 +
                                  kq * 4);
      *(float4*)&Ash[b_l * 128 + kq * 4] = v;
    }
    __syncthreads();
    if (ch == 0) mac4(&Xs[ks * 4], 32, &Wl[(ctile * 4) * 544 + ks * 4]);
#pragma unroll
    for (int j = 0; j < 4; ++j)
      mac4(&Ash[j * 32 + ks * 4], 128,
           &Wl[(ctile * 4) * 544 + DD + ch * 128 + j * 32 + ks * 4]);
  }

#pragma unroll
  for (int i = 0; i < 4; ++i)
#pragma unroll
    for (int c = 0; c < 4; ++c) {
      float v = acc[i][c];
      v += __shfl_xor(v, 1);
      v += __shfl_xor(v, 2);
      v += __shfl_xor(v, 4);
      acc[i][c] = v;
    }

  if (ks == 0) {
#pragma unroll
    for (int i = 0; i < 4; ++i)
#pragma unroll
      for (int c = 0; c < 4; ++c)
        Zx[ctile][btile * 4 + i][c] = acc[i][c] + BiasS[ctile * 4 + c];
  }
  __syncthreads();

  if (tid < 128) {
    int b_l = tid >> 2, nn = tid & 3;
    float zi = Zx[0][b_l][nn], zf = Zx[1][b_l][nn];
    float zg = Zx[2][b_l][nn], zo = Zx[3][b_l][nn];
    int bg = b0g + b_l, col = n0 + nn;
    size_t cidx = (size_t)bg * HH + col;
    float cnew = sigf(zf) * cst[cidx] + sigf(zi) * tanhf(zg);
    cst[cidx] = cnew;
    float hv = sigf(zo) * tanhf(cnew);
    hnext[cidx] = hv;
    out[((size_t)bg * TT + t) * HH + col] = hv;
  }
}

extern "C" void kernel_launch(void* const* d_in, const int* in_sizes, int n_in,
                              void* d_out, int out_size, void* d_ws, size_t ws_size,
                              hipStream_t stream) {
  const float* x = (const float*)d_in[0];
  const float* Wx = (const float*)d_in[1];
  const float* Wh = (const float*)d_in[2];
  const float* bv = (const float*)d_in[3];
  float* out = (float*)d_out;
  float* hws = (float*)d_ws;

  // zero: buf0 | buf1 | barrier counters | cst = (3*65536 + 256) * 4 bytes
  hipMemsetAsync(d_ws, 0, (size_t)(3 * 65536 + 256) * 4, stream);

  void* args[] = {(void*)&x, (void*)&Wx, (void*)&Wh,
                  (void*)&bv, (void*)&out, (void*)&hws};
  hipError_t err = hipLaunchCooperativeKernel(
      reinterpret_cast<void*>(lstm_persistent), dim3(256), dim3(512), args, 0,
      stream);
  if (err != hipSuccess) {
    (void)hipGetLastError();
    float* buf0 = hws;
    float* buf1 = hws + BB * HH;
    float* cst = hws + 2 * BB * HH + 256;
    for (int t = 0; t < TT; ++t) {
      const float* hp = (t & 1) ? buf1 : buf0;
      float* hn = (t & 1) ? buf0 : buf1;
      lstm_step<<<dim3(512), dim3(256), 0, stream>>>(x, Wx, Wh, bv, out, hp, hn,
                                                     cst, t);
    }
  }
}

// Round 6
// 2116.105 us; speedup vs baseline: 6.2253x; 3.5419x over previous
//
#include <hip/hip_runtime.h>
#include <hip/hip_fp16.h>
#include <cmath>

#define BB 128
#define TT 365
#define DD 32
#define HH 512
#define G4H 2048  // 4*HH

// ws layout: buf0 fp16 at byte 0 (131072B used) | buf1 fp16 at byte 262144
//            bar at byte 524288 (16 groups x 32 uints = 512 uints used)
//            cst at float-ofs 131328 (fallback only, fp32; fallback never
//            runs concurrently with the persistent kernel's bar usage)
// hipMemsetAsync zeroes [0, 787456) bytes each call (covers all of above).

typedef float f32x4 __attribute__((ext_vector_type(4)));
typedef _Float16 f16x4 __attribute__((ext_vector_type(4)));
typedef _Float16 f16x2 __attribute__((ext_vector_type(2)));

__device__ __forceinline__ float sigf(float z) { return 1.f / (1.f + __expf(-z)); }

__device__ __forceinline__ float dot2(f16x2 a, f16x2 b, float c) {
#if __has_builtin(__builtin_amdgcn_fdot2)
  return __builtin_amdgcn_fdot2(a, b, c, false);
#else
  return c + (float)a.x * (float)b.x + (float)a.y * (float)b.y;
#endif
}

// ---------------------------------------------------------------------------
// Persistent kernel v7: every coherence-relevant instruction identical to
// v2/v6 (agent-scope __hip_atomic_load/store exchange, monotonic-counter
// barrier). v6's counters showed WRITE_SIZE ~ 55B x atomic-op count (31MB/
// step vs 0.3MB algorithmic) -> time tracks ATOMIC OP COUNT. v7 halves it
// structurally: weights held fp16 in LDS (141KB) -> 128 gate-cols/WG ->
// re-tile to 16 batch groups x 8 rows x 16 col-WGs (still 256 WGs x 512
// thr). Load ops 524K -> 262K/step (2 x 8B per thread), store ops 16K -> 8K.
// Compute via v_dot2_f32_f16 (fp16xfp16, fp32 accum): halves VALU inst
// count, removes all unpack cvts; x joins h in one unified K=544 LDS pane
// (rows: [x 32 | h 512], stride 552 -> conflict-free b64 reads).
// h handoff stays fp16 (v6-proven); c stays fp32 in LDS.
// ---------------------------------------------------------------------------
__global__ __launch_bounds__(512, 2)
void lstm_persistent(const float* __restrict__ x,
                     const float* __restrict__ Wx,
                     const float* __restrict__ Wh,
                     const float* __restrict__ bias,
                     float* __restrict__ out,
                     float* __restrict__ hws) {
  __shared__ __align__(16) _Float16 WlH[128 * 552];  // 141312 B
  __shared__ __align__(16) _Float16 AshH[8 * 552];   // 8832 B  [x(32)|h(512)]
  __shared__ __align__(16) float ZxS[8 * 128];       // 4096 B
  __shared__ __align__(16) float Cs[8][32];          // 1024 B
  __shared__ __align__(16) float BiasS[128];         // 512 B
  // total ~155.8 KB -> 1 WG/CU

  const int tid = threadIdx.x;
  const int ks = tid & 7;          // K-split 8: elems [ks*68, ks*68+68)
  const int rt = (tid >> 3) & 1;   // row tile: rows rt*4..rt*4+3
  const int ctile = tid >> 4;      // col tile [0,32): cols ctile*4..+3
  const int wg = blockIdx.x;
  const int bb = wg & 15;          // batch group [0,16), 8 rows each
  const int nb = wg >> 4;          // col-WG [0,16), 32 h-cols each
  const int b0g = bb * 8;
  const int n0 = nb * 32;

  // ---- stage weights as fp16: lanes 0..31 read 32 consecutive cols
  {
    const int cl = tid & 31;
    const int pg = tid >> 5;  // [0,16)
    for (int it = 0; it < 136; ++it) {
      int p = it * 16 + pg;  // [0, 544*4)
      int k = p >> 2, g = p & 3;
      int col = g * HH + n0 + cl;
      float v = (k < DD) ? Wx[k * G4H + col] : Wh[(k - DD) * G4H + col];
      WlH[(g * 32 + cl) * 552 + k] = (_Float16)v;
    }
  }
  if (tid < 128) BiasS[tid] = bias[(tid >> 5) * HH + n0 + (tid & 31)];
  if (tid < 256) Cs[tid >> 5][tid & 31] = 0.f;

  _Float16* hb0 = (_Float16*)hws;               // fp16 h buffers
  _Float16* hb1 = (_Float16*)(hws + BB * HH);
  unsigned int* bar = (unsigned int*)(hws + 2 * BB * HH) + bb * 32;

  __syncthreads();  // WlH ready (h0 = 0 from host-side memset)

  for (int t = 0; t < TT; ++t) {
    const _Float16* hprev = (t & 1) ? hb1 : hb0;
    _Float16* hnext = (t & 1) ? hb0 : hb1;

    // ---- stage x slice into AshH[:, 0:32) as fp16 (plain cached loads)
    if (tid < 256) {
      int r = tid >> 5, c = tid & 31;
      AshH[r * 552 + c] = (_Float16)x[((size_t)(b0g + r) * TT + t) * DD + c];
    }
    // ---- h loads: 2 agent-scope 8B atomic loads per thread (v6 op class)
    unsigned long long pre[2];
#pragma unroll
    for (int r = 0; r < 2; ++r) {
      int idx = r * 512 + tid;
      int rr = idx >> 7, kk = idx & 127;  // row, 4-half group
      pre[r] = __hip_atomic_load(
          (const unsigned long long*)(hprev + (size_t)(b0g + rr) * HH + kk * 4),
          __ATOMIC_RELAXED, __HIP_MEMORY_SCOPE_AGENT);
    }
#pragma unroll
    for (int r = 0; r < 2; ++r) {
      int idx = r * 512 + tid;
      int rr = idx >> 7, kk = idx & 127;
      *(unsigned long long*)&AshH[rr * 552 + DD + kk * 4] = pre[r];
    }
    __syncthreads();

    float acc[4][4];
#pragma unroll
    for (int i = 0; i < 4; ++i)
#pragma unroll
      for (int c = 0; c < 4; ++c) acc[i][c] = 0.f;

    const _Float16* Ab = AshH + (rt * 4) * 552 + ks * 68;
    const _Float16* Wb = WlH + (ctile * 4) * 552 + ks * 68;
#pragma unroll
    for (int q = 0; q < 17; ++q) {
      f16x2 alo[4], ahi[4], wlo[4], whi[4];
#pragma unroll
      for (int i = 0; i < 4; ++i) {
        f16x4 a4 = *(const f16x4*)(Ab + i * 552 + q * 4);
        alo[i] = __builtin_shufflevector(a4, a4, 0, 1);
        ahi[i] = __builtin_shufflevector(a4, a4, 2, 3);
      }
#pragma unroll
      for (int c = 0; c < 4; ++c) {
        f16x4 w4 = *(const f16x4*)(Wb + c * 552 + q * 4);
        wlo[c] = __builtin_shufflevector(w4, w4, 0, 1);
        whi[c] = __builtin_shufflevector(w4, w4, 2, 3);
      }
#pragma unroll
      for (int i = 0; i < 4; ++i)
#pragma unroll
        for (int c = 0; c < 4; ++c) {
          acc[i][c] = dot2(alo[i], wlo[c], acc[i][c]);
          acc[i][c] = dot2(ahi[i], whi[c], acc[i][c]);
        }
    }

    // reduce over ks (lane bits 0..2, intra-wave)
#pragma unroll
    for (int i = 0; i < 4; ++i)
#pragma unroll
      for (int c = 0; c < 4; ++c) {
        float v = acc[i][c];
        v += __shfl_xor(v, 1);
        v += __shfl_xor(v, 2);
        v += __shfl_xor(v, 4);
        acc[i][c] = v;
      }

    if (ks == 0) {
#pragma unroll
      for (int i = 0; i < 4; ++i)
#pragma unroll
        for (int c = 0; c < 4; ++c) {
          int cc = ctile * 4 + c;
          ZxS[(rt * 4 + i) * 128 + cc] = acc[i][c] + BiasS[cc];
        }
    }
    __syncthreads();

    if (tid < 256) {
      int b_l = tid >> 5, nn = tid & 31;
      float zi = ZxS[b_l * 128 + nn];
      float zf = ZxS[b_l * 128 + 32 + nn];
      float zg = ZxS[b_l * 128 + 64 + nn];
      float zo = ZxS[b_l * 128 + 96 + nn];
      float cnew = sigf(zf) * Cs[b_l][nn] + sigf(zi) * tanhf(zg);
      Cs[b_l][nn] = cnew;
      float hv = sigf(zo) * tanhf(cnew);
      int bg = b0g + b_l, col = n0 + nn;
      out[((size_t)bg * TT + t) * HH + col] = hv;  // fp32, 128B/row, coalesced
      // ---- pack 4 consecutive cols into ONE 8B agent-scope atomic store
      int lane = tid & 63;
      int base = lane & ~3;
      float h0 = __shfl(hv, base + 0);
      float h1 = __shfl(hv, base + 1);
      float h2 = __shfl(hv, base + 2);
      float h3 = __shfl(hv, base + 3);
      if ((lane & 3) == 0) {
        union { unsigned long long u; _Float16 h[4]; } pk;
        pk.h[0] = (_Float16)h0;
        pk.h[1] = (_Float16)h1;
        pk.h[2] = (_Float16)h2;
        pk.h[3] = (_Float16)h3;
        __hip_atomic_store(
            (unsigned long long*)(hnext + (size_t)bg * HH + col), pk.u,
            __ATOMIC_RELAXED, __HIP_MEMORY_SCOPE_AGENT);
      }
    }
    __syncthreads();  // drains vmcnt(0): h stores at coherence point

    // per-group barrier (16 WGs): v2's exact proven agent-scope barrier
    if (tid == 0) {
      __hip_atomic_fetch_add(bar, 1u, __ATOMIC_RELAXED,
                             __HIP_MEMORY_SCOPE_AGENT);
      unsigned int target = 16u * (unsigned)(t + 1);
      while (__hip_atomic_load(bar, __ATOMIC_RELAXED,
                               __HIP_MEMORY_SCOPE_AGENT) < target) {
      }
    }
    __syncthreads();
  }
}

// ---------------------------------------------------------------------------
// Fallback: one launch per timestep (kernel-boundary coherence, fp32 h).
// Only used if the cooperative launch is rejected.
// ---------------------------------------------------------------------------
__global__ __launch_bounds__(256, 2)
void lstm_step(const float* __restrict__ x, const float* __restrict__ Wx,
               const float* __restrict__ Wh, const float* __restrict__ bias,
               float* __restrict__ out, const float* __restrict__ hprev,
               float* __restrict__ hnext, float* __restrict__ cst, int t) {
  __shared__ float Wl[16 * 544];
  __shared__ float Ash[32 * 128];
  __shared__ float Xs[32 * 32];
  __shared__ float Zx[4][32][4];
  __shared__ float BiasS[16];

  const int tid = threadIdx.x;
  const int ks = tid & 7;
  const int btile = (tid >> 3) & 7;
  const int ctile = tid >> 6;
  const int wg = blockIdx.x;
  const int bb = wg & 3;
  const int nb = wg >> 2;
  const int b0g = bb * 32;
  const int n0 = nb * 4;

  for (int idx = tid; idx < 16 * 544; idx += 256) {
    int zc = idx & 15, k = idx >> 4;
    int col = (zc >> 2) * HH + n0 + (zc & 3);
    Wl[zc * 544 + k] = (k < DD) ? Wx[k * G4H + col] : Wh[(k - DD) * G4H + col];
  }
  if (tid < 16) BiasS[tid] = bias[(tid >> 2) * HH + n0 + (tid & 3)];

  {
    int b_l = tid >> 3, kq = tid & 7;
    float4 v = *(const float4*)(x + ((size_t)(b0g + b_l) * TT + t) * DD + kq * 4);
    *(float4*)&Xs[b_l * 32 + kq * 4] = v;
  }

  float acc[4][4];
#pragma unroll
  for (int i = 0; i < 4; ++i)
#pragma unroll
    for (int c = 0; c < 4; ++c) acc[i][c] = 0.f;

  auto mac4 = [&](const float* Abase, int rstride, const float* Wbase) {
    float4 a4[4], w4[4];
#pragma unroll
    for (int i = 0; i < 4; ++i)
      a4[i] = *(const float4*)(Abase + (btile * 4 + i) * rstride);
#pragma unroll
    for (int c = 0; c < 4; ++c) w4[c] = *(const float4*)(Wbase + c * 544);
#pragma unroll
    for (int i = 0; i < 4; ++i)
#pragma unroll
      for (int c = 0; c < 4; ++c)
        acc[i][c] += a4[i].x * w4[c].x + a4[i].y * w4[c].y +
                     a4[i].z * w4[c].z + a4[i].w * w4[c].w;
  };

  for (int ch = 0; ch < 4; ++ch) {
    __syncthreads();
    for (int r = 0; r < 4; ++r) {
      int fidx = r * 256 + tid;
      int b_l = fidx >> 5, kq = fidx & 31;
      float4 v = *(const float4*)(hprev + (size_t)(b0g + b_l) * HH + ch * 128 +
                                  kq * 4);
      *(float4*)&Ash[b_l * 128 + kq * 4] = v;
    }
    __syncthreads();
    if (ch == 0) mac4(&Xs[ks * 4], 32, &Wl[(ctile * 4) * 544 + ks * 4]);
#pragma unroll
    for (int j = 0; j < 4; ++j)
      mac4(&Ash[j * 32 + ks * 4], 128,
           &Wl[(ctile * 4) * 544 + DD + ch * 128 + j * 32 + ks * 4]);
  }

#pragma unroll
  for (int i = 0; i < 4; ++i)
#pragma unroll
    for (int c = 0; c < 4; ++c) {
      float v = acc[i][c];
      v += __shfl_xor(v, 1);
      v += __shfl_xor(v, 2);
      v += __shfl_xor(v, 4);
      acc[i][c] = v;
    }

  if (ks == 0) {
#pragma unroll
    for (int i = 0; i < 4; ++i)
#pragma unroll
      for (int c = 0; c < 4; ++c)
        Zx[ctile][btile * 4 + i][c] = acc[i][c] + BiasS[ctile * 4 + c];
  }
  __syncthreads();

  if (tid < 128) {
    int b_l = tid >> 2, nn = tid & 3;
    float zi = Zx[0][b_l][nn], zf = Zx[1][b_l][nn];
    float zg = Zx[2][b_l][nn], zo = Zx[3][b_l][nn];
    int bg = b0g + b_l, col = n0 + nn;
    size_t cidx = (size_t)bg * HH + col;
    float cnew = sigf(zf) * cst[cidx] + sigf(zi) * tanhf(zg);
    cst[cidx] = cnew;
    float hv = sigf(zo) * tanhf(cnew);
    hnext[cidx] = hv;
    out[((size_t)bg * TT + t) * HH + col] = hv;
  }
}

extern "C" void kernel_launch(void* const* d_in, const int* in_sizes, int n_in,
                              void* d_out, int out_size, void* d_ws, size_t ws_size,
                              hipStream_t stream) {
  const float* x = (const float*)d_in[0];
  const float* Wx = (const float*)d_in[1];
  const float* Wh = (const float*)d_in[2];
  const float* bv = (const float*)d_in[3];
  float* out = (float*)d_out;
  float* hws = (float*)d_ws;

  // zero: buf0 | buf1 | barrier counters | cst = (3*65536 + 256) * 4 bytes
  hipMemsetAsync(d_ws, 0, (size_t)(3 * 65536 + 256) * 4, stream);

  void* args[] = {(void*)&x, (void*)&Wx, (void*)&Wh,
                  (void*)&bv, (void*)&out, (void*)&hws};
  hipError_t err = hipLaunchCooperativeKernel(
      reinterpret_cast<void*>(lstm_persistent), dim3(256), dim3(512), args, 0,
      stream);
  if (err != hipSuccess) {
    (void)hipGetLastError();
    float* buf0 = hws;
    float* buf1 = hws + BB * HH;
    float* cst = hws + 2 * BB * HH + 256;
    for (int t = 0; t < TT; ++t) {
      const float* hp = (t & 1) ? buf1 : buf0;
      float* hn = (t & 1) ? buf0 : buf1;
      lstm_step<<<dim3(512), dim3(256), 0, stream>>>(x, Wx, Wh, bv, out, hp, hn,
                                                     cst, t);
    }
  }
}

// Round 7
// 1085.976 us; speedup vs baseline: 12.1305x; 1.9486x over previous
//
#include <hip/hip_runtime.h>
#include <hip/hip_fp16.h>
#include <cmath>

#define BB 128
#define TT 365
#define DD 32
#define HH 512
#define G4H 2048  // 4*HH

// ws layout: buf0 fp16 at byte 0 (131072B used) | buf1 fp16 at byte 262144
//            bar at byte 524288 (16 groups x 32 uints = 512 uints used)
//            cst at float-ofs 131328 (fallback only, fp32)
// hipMemsetAsync zeroes [0, 787456) bytes each call (covers all of above).

typedef float f32x4 __attribute__((ext_vector_type(4)));
typedef _Float16 f16x8 __attribute__((ext_vector_type(8)));

__device__ __forceinline__ float sigf(float z) { return 1.f / (1.f + __expf(-z)); }

// ---------------------------------------------------------------------------
// Persistent kernel v8: tiling and EVERY coherence-relevant instruction
// identical to v7 (2116us, passed): 256 WGs x 512 thr, 16 batch groups x 8
// rows x 16 col-WGs (128 gate-cols/WG), fp16 h exchange via agent-scope
// __hip_atomic_load/store, v2's monotonic barrier, same sync placement.
// v7's counters: HBM ~1% peak (exchange is cache-resident now), VALUBusy 41%
// -> the dot2 inner loop (~2.4us/step) + sync/latency (~3.4us) ARE the step.
// v8 replaces dot2 with mfma_f32_16x16x32_f16: wave w owns output cols
// [w*16,w*16+16); its 17 B-fragments (K=544) are loaded ONCE into 68 VGPRs
// at init (W is step-invariant) and reused 365 steps. Per step per wave:
// 17 x (masked ds_read_b128 A-frag + MFMA) ~= 300 cycles. M=8 padded to 16
// (lanes with row>=8 feed zeros). Also: out-store moved AFTER the barrier
// arrive, overlapping its HBM ack with the poll.
// MFMA layouts (std CDNA): A row=lane&15, k=(lane>>4)*8+j; B col=lane&15,
// same k; C/D col=lane&15, row=(lane>>4)*4+reg (guide-verified, 16x16 shape).
// ---------------------------------------------------------------------------
__global__ __launch_bounds__(512, 2)
void lstm_persistent(const float* __restrict__ x,
                     const float* __restrict__ Wx,
                     const float* __restrict__ Wh,
                     const float* __restrict__ bias,
                     float* __restrict__ out,
                     float* __restrict__ hws) {
  __shared__ __align__(16) _Float16 WlH[128 * 552];  // 141312 B (init staging + bfrag source)
  __shared__ __align__(16) _Float16 AshH[8 * 552];   // 8832 B  [x(32)|h(512)] per row
  __shared__ __align__(16) float ZxS[8 * 128];       // 4096 B
  __shared__ __align__(16) float Cs[8][32];          // 1024 B
  __shared__ __align__(16) float BiasS[128];         // 512 B
  // total ~155.8 KB -> 1 WG/CU

  const int tid = threadIdx.x;
  const int lane = tid & 63;
  const int wv = tid >> 6;             // wave id [0,8)
  const int fcol = wv * 16 + (lane & 15);  // this lane's output col [0,128)
  const int kq = lane >> 4;            // k-subgroup [0,4): k-offset kq*8
  const int arow = lane & 15;          // A-fragment row (valid if <8)
  const int wg = blockIdx.x;
  const int bb = wg & 15;              // batch group [0,16), 8 rows each
  const int nb = wg >> 4;              // col-WG [0,16), 32 h-cols each
  const int b0g = bb * 8;
  const int n0 = nb * 32;

  // ---- stage weights as fp16: lanes 0..31 read 32 consecutive cols
  {
    const int cl = tid & 31;
    const int pg = tid >> 5;  // [0,16)
    for (int it = 0; it < 136; ++it) {
      int p = it * 16 + pg;  // [0, 544*4)
      int k = p >> 2, g = p & 3;
      int col = g * HH + n0 + cl;
      float v = (k < DD) ? Wx[k * G4H + col] : Wh[(k - DD) * G4H + col];
      WlH[(g * 32 + cl) * 552 + k] = (_Float16)v;
    }
  }
  if (tid < 128) BiasS[tid] = bias[(tid >> 5) * HH + n0 + (tid & 31)];
  if (tid < 256) Cs[tid >> 5][tid & 31] = 0.f;

  _Float16* hb0 = (_Float16*)hws;               // fp16 h buffers
  _Float16* hb1 = (_Float16*)(hws + BB * HH);
  unsigned int* bar = (unsigned int*)(hws + 2 * BB * HH) + bb * 32;

  __syncthreads();  // WlH ready

  // ---- hoist this wave's B-fragments into registers (persist 365 steps)
  f16x8 bfrag[17];
#pragma unroll
  for (int kk = 0; kk < 17; ++kk)
    bfrag[kk] = *(const f16x8*)&WlH[fcol * 552 + kk * 32 + kq * 8];

  for (int t = 0; t < TT; ++t) {
    const _Float16* hprev = (t & 1) ? hb1 : hb0;
    _Float16* hnext = (t & 1) ? hb0 : hb1;

    // ---- stage x slice into AshH[:, 0:32) as fp16 (plain cached loads)
    if (tid < 256) {
      int r = tid >> 5, c = tid & 31;
      AshH[r * 552 + c] = (_Float16)x[((size_t)(b0g + r) * TT + t) * DD + c];
    }
    // ---- h loads: 2 agent-scope 8B atomic loads per thread (v6/v7 op class)
    unsigned long long pre[2];
#pragma unroll
    for (int r = 0; r < 2; ++r) {
      int idx = r * 512 + tid;
      int rr = idx >> 7, kk = idx & 127;  // row, 4-half group
      pre[r] = __hip_atomic_load(
          (const unsigned long long*)(hprev + (size_t)(b0g + rr) * HH + kk * 4),
          __ATOMIC_RELAXED, __HIP_MEMORY_SCOPE_AGENT);
    }
#pragma unroll
    for (int r = 0; r < 2; ++r) {
      int idx = r * 512 + tid;
      int rr = idx >> 7, kk = idx & 127;
      *(unsigned long long*)&AshH[rr * 552 + DD + kk * 4] = pre[r];
    }
    __syncthreads();  // AshH ready

    // ---- MFMA: Z[16(8 valid) x 16] per wave, K=544 in 17 steps
    f32x4 acc = {0.f, 0.f, 0.f, 0.f};
#pragma unroll
    for (int kk = 0; kk < 17; ++kk) {
      f16x8 af;
      if (arow < 8) {
        af = *(const f16x8*)&AshH[arow * 552 + kk * 32 + kq * 8];
      } else {
        f16x8 z = {};
        af = z;
      }
      acc = __builtin_amdgcn_mfma_f32_16x16x32_f16(af, bfrag[kk], acc, 0, 0, 0);
    }
    // C/D: col=lane&15 (-> fcol), row=(lane>>4)*4+r; rows 0..7 valid
    if (kq < 2) {
#pragma unroll
      for (int r = 0; r < 4; ++r)
        ZxS[(kq * 4 + r) * 128 + fcol] = acc[r] + BiasS[fcol];
    }
    __syncthreads();  // ZxS ready

    float hv = 0.f;
    int bg = 0, col = 0;
    if (tid < 256) {
      int b_l = tid >> 5, nn = tid & 31;
      float zi = ZxS[b_l * 128 + nn];
      float zf = ZxS[b_l * 128 + 32 + nn];
      float zg = ZxS[b_l * 128 + 64 + nn];
      float zo = ZxS[b_l * 128 + 96 + nn];
      float cnew = sigf(zf) * Cs[b_l][nn] + sigf(zi) * tanhf(zg);
      Cs[b_l][nn] = cnew;
      hv = sigf(zo) * tanhf(cnew);
      bg = b0g + b_l;
      col = n0 + nn;
      // ---- pack 4 consecutive cols into ONE 8B agent-scope atomic store
      int base = lane & ~3;
      float h0 = __shfl(hv, base + 0);
      float h1 = __shfl(hv, base + 1);
      float h2 = __shfl(hv, base + 2);
      float h3 = __shfl(hv, base + 3);
      if ((lane & 3) == 0) {
        union { unsigned long long u; _Float16 h[4]; } pk;
        pk.h[0] = (_Float16)h0;
        pk.h[1] = (_Float16)h1;
        pk.h[2] = (_Float16)h2;
        pk.h[3] = (_Float16)h3;
        __hip_atomic_store(
            (unsigned long long*)(hnext + (size_t)bg * HH + col), pk.u,
            __ATOMIC_RELAXED, __HIP_MEMORY_SCOPE_AGENT);
      }
    }
    __syncthreads();  // drains vmcnt(0): h stores at coherence point

    // arrive FIRST, then the out store overlaps the poll
    if (tid == 0) {
      __hip_atomic_fetch_add(bar, 1u, __ATOMIC_RELAXED,
                             __HIP_MEMORY_SCOPE_AGENT);
    }
    if (tid < 256) {
      out[((size_t)bg * TT + t) * HH + col] = hv;  // fp32, coalesced
    }
    if (tid == 0) {
      unsigned int target = 16u * (unsigned)(t + 1);
      while (__hip_atomic_load(bar, __ATOMIC_RELAXED,
                               __HIP_MEMORY_SCOPE_AGENT) < target) {
      }
    }
    __syncthreads();
  }
}

// ---------------------------------------------------------------------------
// Fallback: one launch per timestep (kernel-boundary coherence, fp32 h).
// Only used if the cooperative launch is rejected.
// ---------------------------------------------------------------------------
__global__ __launch_bounds__(256, 2)
void lstm_step(const float* __restrict__ x, const float* __restrict__ Wx,
               const float* __restrict__ Wh, const float* __restrict__ bias,
               float* __restrict__ out, const float* __restrict__ hprev,
               float* __restrict__ hnext, float* __restrict__ cst, int t) {
  __shared__ float Wl[16 * 544];
  __shared__ float Ash[32 * 128];
  __shared__ float Xs[32 * 32];
  __shared__ float Zx[4][32][4];
  __shared__ float BiasS[16];

  const int tid = threadIdx.x;
  const int ks = tid & 7;
  const int btile = (tid >> 3) & 7;
  const int ctile = tid >> 6;
  const int wg = blockIdx.x;
  const int bb = wg & 3;
  const int nb = wg >> 2;
  const int b0g = bb * 32;
  const int n0 = nb * 4;

  for (int idx = tid; idx < 16 * 544; idx += 256) {
    int zc = idx & 15, k = idx >> 4;
    int col = (zc >> 2) * HH + n0 + (zc & 3);
    Wl[zc * 544 + k] = (k < DD) ? Wx[k * G4H + col] : Wh[(k - DD) * G4H + col];
  }
  if (tid < 16) BiasS[tid] = bias[(tid >> 2) * HH + n0 + (tid & 3)];

  {
    int b_l = tid >> 3, kq = tid & 7;
    float4 v = *(const float4*)(x + ((size_t)(b0g + b_l) * TT + t) * DD + kq * 4);
    *(float4*)&Xs[b_l * 32 + kq * 4] = v;
  }

  float acc[4][4];
#pragma unroll
  for (int i = 0; i < 4; ++i)
#pragma unroll
    for (int c = 0; c < 4; ++c) acc[i][c] = 0.f;

  auto mac4 = [&](const float* Abase, int rstride, const float* Wbase) {
    float4 a4[4], w4[4];
#pragma unroll
    for (int i = 0; i < 4; ++i)
      a4[i] = *(const float4*)(Abase + (btile * 4 + i) * rstride);
#pragma unroll
    for (int c = 0; c < 4; ++c) w4[c] = *(const float4*)(Wbase + c * 544);
#pragma unroll
    for (int i = 0; i < 4; ++i)
#pragma unroll
      for (int c = 0; c < 4; ++c)
        acc[i][c] += a4[i].x * w4[c].x + a4[i].y * w4[c].y +
                     a4[i].z * w4[c].z + a4[i].w * w4[c].w;
  };

  for (int ch = 0; ch < 4; ++ch) {
    __syncthreads();
    for (int r = 0; r < 4; ++r) {
      int fidx = r * 256 + tid;
      int b_l = fidx >> 5, kq = fidx & 31;
      float4 v = *(const float4*)(hprev + (size_t)(b0g + b_l) * HH + ch * 128 +
                                  kq * 4);
      *(float4*)&Ash[b_l * 128 + kq * 4] = v;
    }
    __syncthreads();
    if (ch == 0) mac4(&Xs[ks * 4], 32, &Wl[(ctile * 4) * 544 + ks * 4]);
#pragma unroll
    for (int j = 0; j < 4; ++j)
      mac4(&Ash[j * 32 + ks * 4], 128,
           &Wl[(ctile * 4) * 544 + DD + ch * 128 + j * 32 + ks * 4]);
  }

#pragma unroll
  for (int i = 0; i < 4; ++i)
#pragma unroll
    for (int c = 0; c < 4; ++c) {
      float v = acc[i][c];
      v += __shfl_xor(v, 1);
      v += __shfl_xor(v, 2);
      v += __shfl_xor(v, 4);
      acc[i][c] = v;
    }

  if (ks == 0) {
#pragma unroll
    for (int i = 0; i < 4; ++i)
#pragma unroll
      for (int c = 0; c < 4; ++c)
        Zx[ctile][btile * 4 + i][c] = acc[i][c] + BiasS[ctile * 4 + c];
  }
  __syncthreads();

  if (tid < 128) {
    int b_l = tid >> 2, nn = tid & 3;
    float zi = Zx[0][b_l][nn], zf = Zx[1][b_l][nn];
    float zg = Zx[2][b_l][nn], zo = Zx[3][b_l][nn];
    int bg = b0g + b_l, col = n0 + nn;
    size_t cidx = (size_t)bg * HH + col;
    float cnew = sigf(zf) * cst[cidx] + sigf(zi) * tanhf(zg);
    cst[cidx] = cnew;
    float hv = sigf(zo) * tanhf(cnew);
    hnext[cidx] = hv;
    out[((size_t)bg * TT + t) * HH + col] = hv;
  }
}

extern "C" void kernel_launch(void* const* d_in, const int* in_sizes, int n_in,
                              void* d_out, int out_size, void* d_ws, size_t ws_size,
                              hipStream_t stream) {
  const float* x = (const float*)d_in[0];
  const float* Wx = (const float*)d_in[1];
  const float* Wh = (const float*)d_in[2];
  const float* bv = (const float*)d_in[3];
  float* out = (float*)d_out;
  float* hws = (float*)d_ws;

  // zero: buf0 | buf1 | barrier counters | cst = (3*65536 + 256) * 4 bytes
  hipMemsetAsync(d_ws, 0, (size_t)(3 * 65536 + 256) * 4, stream);

  void* args[] = {(void*)&x, (void*)&Wx, (void*)&Wh,
                  (void*)&bv, (void*)&out, (void*)&hws};
  hipError_t err = hipLaunchCooperativeKernel(
      reinterpret_cast<void*>(lstm_persistent), dim3(256), dim3(512), args, 0,
      stream);
  if (err != hipSuccess) {
    (void)hipGetLastError();
    float* buf0 = hws;
    float* buf1 = hws + BB * HH;
    float* cst = hws + 2 * BB * HH + 256;
    for (int t = 0; t < TT; ++t) {
      const float* hp = (t & 1) ? buf1 : buf0;
      float* hn = (t & 1) ? buf0 : buf1;
      lstm_step<<<dim3(512), dim3(256), 0, stream>>>(x, Wx, Wh, bv, out, hp, hn,
                                                     cst, t);
    }
  }
}